// Round 5
// baseline (355.333 us; speedup 1.0000x reference)
//
#include <hip/hip_runtime.h>
#include <hip/hip_bf16.h>

// TurboQuantMSE: x_hat = Q(x @ R^T) @ R, Q = 16-level Lloyd-Max quantizer.
// fp16 MFMA GEMMs, 128x256 tile, BK=64, 8 waves. Round 5: A-fragments are
// REGISTER-RESIDENT (loaded straight from global/L2, prefetched 1 tile ahead);
// LDS carries B only (3 buffers x 32KB, counted vmcnt(4) boundary). This
// takes the LDS port from ~2112 cyc/K-tile (oversubscribed vs 1242 MFMA) to
// ~768, making the kernel MFMA-bound. T2 swizzle on B, T5 setprio.

typedef __attribute__((ext_vector_type(8))) _Float16 f16x8;
typedef __attribute__((ext_vector_type(4))) float f32x4;

__device__ __forceinline__ unsigned short f2h(float f) {
    _Float16 h = (_Float16)f;
    return *reinterpret_cast<unsigned short*>(&h);
}

// ---------------- elementwise f32 -> fp16 (x) ----------------
__global__ __launch_bounds__(256) void convert_x_kernel(
    const float* __restrict__ x, unsigned short* __restrict__ xb) {
    const int i = (blockIdx.x * 256 + threadIdx.x) * 4;
    float4 v = *reinterpret_cast<const float4*>(x + i);
    ushort4 b;
    b.x = f2h(v.x); b.y = f2h(v.y); b.z = f2h(v.z); b.w = f2h(v.w);
    *reinterpret_cast<ushort4*>(xb + i) = b;
}

// ---------------- rotation f32 -> fp16 (row-major) + fp16 transposed --------
__global__ __launch_bounds__(256) void conv_rot_kernel(
    const float* __restrict__ R, unsigned short* __restrict__ Rb,
    unsigned short* __restrict__ Rt) {
    __shared__ float t[64][65];
    const int tid = threadIdx.x;
    const int tr = blockIdx.y * 64, tc = blockIdx.x * 64;
    const int r0 = tid >> 4;
    const int c4 = (tid & 15) << 2;
#pragma unroll
    for (int i = 0; i < 4; i++) {
        const int r = r0 + i * 16;
        float4 v = *reinterpret_cast<const float4*>(
            &R[(size_t)(tr + r) * 4096 + tc + c4]);
        ushort4 b;
        b.x = f2h(v.x); b.y = f2h(v.y); b.z = f2h(v.z); b.w = f2h(v.w);
        *reinterpret_cast<ushort4*>(&Rb[(size_t)(tr + r) * 4096 + tc + c4]) = b;
        t[r][c4 + 0] = v.x; t[r][c4 + 1] = v.y;
        t[r][c4 + 2] = v.z; t[r][c4 + 3] = v.w;
    }
    __syncthreads();
#pragma unroll
    for (int i = 0; i < 16; i++) {
        const int idx = tid + 256 * i;
        const int rr = idx >> 6;
        const int cc = idx & 63;
        Rt[(size_t)(tc + rr) * 4096 + tr + cc] = f2h(t[cc][rr]);
    }
}

// ---------------- phased NT GEMM, reg-resident A ----------------------------
// C[2048,4096] = A[2048,K] * Bt[4096,K]^T, fp16 in, f32 accum.
// BM=128 BN=256 BK=64, 8 waves (2M x 4N), per-wave 64x64 (4x4 frags).
// A-frags: global->reg, prefetched 1 tile ahead. B: 3 LDS buffers x 32KB,
// staged 2 tiles ahead, XOR-swizzled. Boundary: counted vmcnt(4).
constexpr int GK = 4096;
constexpr int BM = 128, BN = 256, BK = 64;
constexpr int NT = GK / BK;                 // 64
constexpr int BUF = BN * BK * 2;            // 32768
constexpr int LDS_DYN = 3 * BUF;            // 98304

template <bool QUANT>
__global__ __launch_bounds__(512, 2) void gemm_nt_kernel(
    const unsigned short* __restrict__ A, const unsigned short* __restrict__ Bt,
    void* __restrict__ Cout, const float* __restrict__ cb16) {
    extern __shared__ char smem[];
    const int tid = threadIdx.x;
    const int lane = tid & 63;
    const int w = tid >> 6;        // 0..7
    const int wm = w >> 2;         // 0..1
    const int wn = w & 3;          // 0..3

    // XCD-aware bijective swizzle (256 blocks, 256%8==0)
    const int bid = blockIdx.x;
    const int wgid = (bid & 7) * 32 + (bid >> 3);
    const int tn = wgid & 15;      // N/BN = 16
    const int tm = wgid >> 4;      // M/BM = 16

    f32x4 acc[4][4];
#pragma unroll
    for (int m = 0; m < 4; m++)
#pragma unroll
        for (int n = 0; n < 4; n++) acc[m][n] = (f32x4){0.f, 0.f, 0.f, 0.f};

    // ---- A-fragment running pointers (per m-frag), advance 64 elts/tile ----
    const unsigned short* Ap0 = A +
        (size_t)(tm * BM + wm * 64 + 0 * 16 + (lane & 15)) * GK + ((lane >> 4) << 3);
    const unsigned short* Ap1 = Ap0 + (size_t)16 * GK;
    const unsigned short* Ap2 = Ap0 + (size_t)32 * GK;
    const unsigned short* Ap3 = Ap0 + (size_t)48 * GK;

    // ---- B staging (pre-swizzled global source, linear LDS dest) ----
    const int srow = tid >> 3;                              // 0..63
    const int scol = (((tid & 7) ^ (srow & 7)) << 3);       // elements
    const unsigned short* Bp0 = Bt +
        (size_t)(tn * BN + 0 * 64 + srow) * GK + scol;
    const unsigned short* Bp1 = Bp0 + (size_t)64 * GK;
    const unsigned short* Bp2 = Bp0 + (size_t)128 * GK;
    const unsigned short* Bp3 = Bp0 + (size_t)192 * GK;
    const int wbase = (w << 10);                            // w*1024 B

#define STAGE_B(dstbase)                                                       \
    {                                                                          \
        __builtin_amdgcn_global_load_lds(                                      \
            (const __attribute__((address_space(1))) void*)Bp0,                \
            (__attribute__((address_space(3))) void*)(smem + (dstbase) + 0 * 8192 + wbase), 16, 0, 0); \
        __builtin_amdgcn_global_load_lds(                                      \
            (const __attribute__((address_space(1))) void*)Bp1,                \
            (__attribute__((address_space(3))) void*)(smem + (dstbase) + 1 * 8192 + wbase), 16, 0, 0); \
        __builtin_amdgcn_global_load_lds(                                      \
            (const __attribute__((address_space(1))) void*)Bp2,                \
            (__attribute__((address_space(3))) void*)(smem + (dstbase) + 2 * 8192 + wbase), 16, 0, 0); \
        __builtin_amdgcn_global_load_lds(                                      \
            (const __attribute__((address_space(1))) void*)Bp3,                \
            (__attribute__((address_space(3))) void*)(smem + (dstbase) + 3 * 8192 + wbase), 16, 0, 0); \
        Bp0 += BK; Bp1 += BK; Bp2 += BK; Bp3 += BK;                            \
    }

    // ---- B fragment read addressing (swizzled) ----
    const int brow = (wn * 64 + (lane & 15)) * 128;           // B row byte
    const int slotx = lane >> 4;                              // 0..3
    const int sw0 = ((slotx ^ (lane & 7)) << 4);              // kk=0
    const int sw1 = (((4 + slotx) ^ (lane & 7)) << 4);        // kk=1

#define LDB(n, sw) (*reinterpret_cast<const f16x8*>(smem + lb + brow + (n) * 2048 + (sw)))
#define MFMA_ROW(aR, r)                                                          \
    acc[r][0] = __builtin_amdgcn_mfma_f32_16x16x32_f16(aR, b0, acc[r][0], 0, 0, 0); \
    acc[r][1] = __builtin_amdgcn_mfma_f32_16x16x32_f16(aR, b1, acc[r][1], 0, 0, 0); \
    acc[r][2] = __builtin_amdgcn_mfma_f32_16x16x32_f16(aR, b2, acc[r][2], 0, 0, 0); \
    acc[r][3] = __builtin_amdgcn_mfma_f32_16x16x32_f16(aR, b3, acc[r][3], 0, 0, 0);
#define PH_SYNC                                        \
    __builtin_amdgcn_s_barrier();                      \
    asm volatile("s_waitcnt lgkmcnt(0)" ::: "memory"); \
    __builtin_amdgcn_sched_barrier(0);

    // A frags: AC##k, k = m*2 + kk (m-frag 0..3, kk half 0..1)
    f16x8 aA0, aA1, aA2, aA3, aA4, aA5, aA6, aA7;
    f16x8 aB0, aB1, aB2, aB3, aB4, aB5, aB6, aB7;

#define LOAD_A(AN)                                              \
    {                                                           \
        AN##0 = *reinterpret_cast<const f16x8*>(Ap0);           \
        AN##1 = *reinterpret_cast<const f16x8*>(Ap0 + 32);      \
        AN##2 = *reinterpret_cast<const f16x8*>(Ap1);           \
        AN##3 = *reinterpret_cast<const f16x8*>(Ap1 + 32);      \
        AN##4 = *reinterpret_cast<const f16x8*>(Ap2);           \
        AN##5 = *reinterpret_cast<const f16x8*>(Ap2 + 32);      \
        AN##6 = *reinterpret_cast<const f16x8*>(Ap3);           \
        AN##7 = *reinterpret_cast<const f16x8*>(Ap3 + 32);      \
        Ap0 += BK; Ap1 += BK; Ap2 += BK; Ap3 += BK;             \
    }

    // ---- prologue: B(t0)->buf0, A(t0)->regs, B(t1)->buf1; wait vmcnt(4) ----
    STAGE_B(0)
    LOAD_A(aA)
    STAGE_B(BUF)
    asm volatile("s_waitcnt vmcnt(4)" ::: "memory");
    __builtin_amdgcn_s_barrier();
    __builtin_amdgcn_sched_barrier(0);

    int lb = 0;            // buffer holding tile t's B
    int wb = 2 * BUF;      // buffer to write tile t+2's B

#define TILE_BODY(AC, AN, t)                                                   \
    {                                                                          \
        f16x8 b0, b1, b2, b3;                                                  \
        /* phase 0: kk=0 */                                                    \
        b0 = LDB(0, sw0); b1 = LDB(1, sw0); b2 = LDB(2, sw0); b3 = LDB(3, sw0);\
        if ((t) + 1 < NT) LOAD_A(AN)                                           \
        PH_SYNC                                                                \
        __builtin_amdgcn_s_setprio(1);                                         \
        MFMA_ROW(AC##0, 0) MFMA_ROW(AC##2, 1) MFMA_ROW(AC##4, 2) MFMA_ROW(AC##6, 3) \
        __builtin_amdgcn_s_setprio(0);                                         \
        __builtin_amdgcn_s_barrier();                                          \
        /* phase 1: kk=1 */                                                    \
        b0 = LDB(0, sw1); b1 = LDB(1, sw1); b2 = LDB(2, sw1); b3 = LDB(3, sw1);\
        if ((t) + 2 < NT) STAGE_B(wb)                                          \
        PH_SYNC                                                                \
        __builtin_amdgcn_s_setprio(1);                                         \
        MFMA_ROW(AC##1, 0) MFMA_ROW(AC##3, 1) MFMA_ROW(AC##5, 2) MFMA_ROW(AC##7, 3) \
        __builtin_amdgcn_s_setprio(0);                                         \
        /* tile boundary: counted wait (A(t+1) + B(t+1) landed) */             \
        if ((t) + 1 < NT) {                                                    \
            if ((t) + 2 < NT) {                                                \
                asm volatile("s_waitcnt vmcnt(4)" ::: "memory");               \
            } else {                                                           \
                asm volatile("s_waitcnt vmcnt(0)" ::: "memory");               \
            }                                                                  \
            __builtin_amdgcn_s_barrier();                                      \
            __builtin_amdgcn_sched_barrier(0);                                 \
            lb = (lb == 2 * BUF) ? 0 : lb + BUF;                               \
            wb = (wb == 2 * BUF) ? 0 : wb + BUF;                               \
        }                                                                      \
    }

    for (int t = 0; t < NT; t += 2) {
        TILE_BODY(aA, aB, t)
        TILE_BODY(aB, aA, t + 1)
    }
#undef TILE_BODY
#undef LOAD_A
#undef STAGE_B
#undef LDB
#undef MFMA_ROW
#undef PH_SYNC

    // ---- epilogue: C/D layout col=lane&15, row=(lane>>4)*4+j ----
    const int crow0 = tm * BM + wm * 64 + ((lane >> 4) << 2);
    const int ccol0 = tn * BN + wn * 64 + (lane & 15);
    if constexpr (QUANT) {
        float c[16];
#pragma unroll
        for (int i = 0; i < 16; i++) c[i] = cb16[i];
        unsigned short* O = (unsigned short*)Cout;
#pragma unroll
        for (int m = 0; m < 4; m++)
#pragma unroll
            for (int n = 0; n < 4; n++)
#pragma unroll
                for (int j = 0; j < 4; j++) {
                    const float yn = acc[m][n][j] * 64.0f;
                    float v = c[0];
#pragma unroll
                    for (int i = 0; i < 15; i++) {
                        const float bnd = 0.5f * (c[i] + c[i + 1]);
                        v = (yn > bnd) ? c[i + 1] : v;
                    }
                    O[(size_t)(crow0 + m * 16 + j) * 4096 + ccol0 + n * 16] =
                        f2h(v * 0.015625f);
                }
    } else {
        float* O = (float*)Cout;
#pragma unroll
        for (int m = 0; m < 4; m++)
#pragma unroll
            for (int n = 0; n < 4; n++)
#pragma unroll
                for (int j = 0; j < 4; j++)
                    O[(size_t)(crow0 + m * 16 + j) * 4096 + ccol0 + n * 16] =
                        acc[m][n][j];
    }
}

extern "C" void kernel_launch(void* const* d_in, const int* in_sizes, int n_in,
                              void* d_out, int out_size, void* d_ws,
                              size_t ws_size, hipStream_t stream) {
    const float* x = (const float*)d_in[0];
    const float* rot = (const float*)d_in[1];
    const float* cb = (const float*)d_in[2];
    float* out = (float*)d_out;

    unsigned short* Xh = (unsigned short*)d_ws;
    unsigned short* Rh = Xh + (size_t)2048 * 4096;
    unsigned short* Rt = Rh + (size_t)4096 * 4096;
    unsigned short* Yh = Rt + (size_t)4096 * 4096;

    (void)hipFuncSetAttribute(
        reinterpret_cast<const void*>(&gemm_nt_kernel<true>),
        hipFuncAttributeMaxDynamicSharedMemorySize, LDS_DYN);
    (void)hipFuncSetAttribute(
        reinterpret_cast<const void*>(&gemm_nt_kernel<false>),
        hipFuncAttributeMaxDynamicSharedMemorySize, LDS_DYN);

    convert_x_kernel<<<8192, 256, 0, stream>>>(x, Xh);
    conv_rot_kernel<<<dim3(64, 64), 256, 0, stream>>>(rot, Rh, Rt);
    // y = x @ R^T : NT GEMM, Bt = Rh
    gemm_nt_kernel<true><<<256, 512, LDS_DYN, stream>>>(Xh, Rh, (void*)Yh, cb);
    // x_hat = y_hat @ R = y_hat @ (R^T)^T : NT GEMM, Bt = Rt
    gemm_nt_kernel<false><<<256, 512, LDS_DYN, stream>>>(Yh, Rt, (void*)out, nullptr);
}

// Round 6
// 176.414 us; speedup vs baseline: 2.0142x; 2.0142x over previous
//
#include <hip/hip_runtime.h>
#include <hip/hip_bf16.h>

// TurboQuantMSE: x_hat = Q(x @ R^T) @ R, Q = 16-level Lloyd-Max quantizer.
// fp16 MFMA GEMMs, 128x256 tile, 8 waves. Round 6: BK=32 + 3-buffer LDS
// (3 x 24KB = 72KB) -> 2 blocks/CU so cross-block overlap hides the
// barrier-ganged stalls (R3-R5 showed 1 block/CU is sync-bound, nothing
// saturated). One barrier per K-tile, counted vmcnt(3) boundary, 2-way-free
// LDS swizzle (slot ^= (row>>1)&3 on 64B rows), setprio around MFMA cluster.

typedef __attribute__((ext_vector_type(8))) _Float16 f16x8;
typedef __attribute__((ext_vector_type(4))) float f32x4;

__device__ __forceinline__ unsigned short f2h(float f) {
    _Float16 h = (_Float16)f;
    return *reinterpret_cast<unsigned short*>(&h);
}

// ---------------- elementwise f32 -> fp16 (x) ----------------
__global__ __launch_bounds__(256) void convert_x_kernel(
    const float* __restrict__ x, unsigned short* __restrict__ xb) {
    const int i = (blockIdx.x * 256 + threadIdx.x) * 4;
    float4 v = *reinterpret_cast<const float4*>(x + i);
    ushort4 b;
    b.x = f2h(v.x); b.y = f2h(v.y); b.z = f2h(v.z); b.w = f2h(v.w);
    *reinterpret_cast<ushort4*>(xb + i) = b;
}

// ---------------- rotation f32 -> fp16 (row-major) + fp16 transposed --------
__global__ __launch_bounds__(256) void conv_rot_kernel(
    const float* __restrict__ R, unsigned short* __restrict__ Rb,
    unsigned short* __restrict__ Rt) {
    __shared__ float t[64][65];
    const int tid = threadIdx.x;
    const int tr = blockIdx.y * 64, tc = blockIdx.x * 64;
    const int r0 = tid >> 4;
    const int c4 = (tid & 15) << 2;
#pragma unroll
    for (int i = 0; i < 4; i++) {
        const int r = r0 + i * 16;
        float4 v = *reinterpret_cast<const float4*>(
            &R[(size_t)(tr + r) * 4096 + tc + c4]);
        ushort4 b;
        b.x = f2h(v.x); b.y = f2h(v.y); b.z = f2h(v.z); b.w = f2h(v.w);
        *reinterpret_cast<ushort4*>(&Rb[(size_t)(tr + r) * 4096 + tc + c4]) = b;
        t[r][c4 + 0] = v.x; t[r][c4 + 1] = v.y;
        t[r][c4 + 2] = v.z; t[r][c4 + 3] = v.w;
    }
    __syncthreads();
#pragma unroll
    for (int i = 0; i < 16; i++) {
        const int idx = tid + 256 * i;
        const int rr = idx >> 6;
        const int cc = idx & 63;
        Rt[(size_t)(tc + rr) * 4096 + tr + cc] = f2h(t[cc][rr]);
    }
}

// ---------------- pipelined NT GEMM -----------------------------------------
// C[2048,4096] = A[2048,K] * Bt[4096,K]^T, fp16 in, f32 accum.
// BM=128 BN=256 BK=32, 8 waves (2M x 4N), per-wave 64x64 (4x4 frags).
// LDS rows are 64B (32 fp16). A region 8KB + B region 16KB = 24KB/buffer,
// 3 buffers. 3 staging chunks/tile (A:1, B:2), staged 2 tiles ahead.
// Per tile: {8 ds_read | stage(t+2)x3 | lgkmcnt(0) | 16 MFMA | vmcnt(3) | bar}
constexpr int GK = 4096;
constexpr int BM = 128, BN = 256, BK = 32;
constexpr int NT = GK / BK;                 // 128
constexpr int A_LDS = BM * BK * 2;          // 8192
constexpr int BUF = (BM + BN) * BK * 2;     // 24576
constexpr int LDS_DYN = 3 * BUF;            // 73728

template <bool QUANT>
__global__ __launch_bounds__(512, 4) void gemm_nt_kernel(
    const unsigned short* __restrict__ A, const unsigned short* __restrict__ Bt,
    void* __restrict__ Cout, const float* __restrict__ cb16) {
    extern __shared__ char smem[];
    const int tid = threadIdx.x;
    const int lane = tid & 63;
    const int w = tid >> 6;        // 0..7
    const int wm = w >> 2;         // 0..1
    const int wn = w & 3;          // 0..3

    // XCD-aware bijective swizzle (256 blocks, 256%8==0)
    const int bid = blockIdx.x;
    const int wgid = (bid & 7) * 32 + (bid >> 3);
    const int tn = wgid & 15;      // N/BN = 16
    const int tm = wgid >> 4;      // M/BM = 16

    f32x4 acc[4][4];
#pragma unroll
    for (int m = 0; m < 4; m++)
#pragma unroll
        for (int n = 0; n < 4; n++) acc[m][n] = (f32x4){0.f, 0.f, 0.f, 0.f};

    // ---- staging: 3 chunks of 8KB (128 rows x 64B). thread: row=tid>>2,
    // slot=tid&3; global col pre-swizzled so linear LDS + swizzled read agree.
    const int srow = tid >> 2;                                  // 0..127
    const int scol = (((tid & 3) ^ ((srow >> 1) & 3)) << 3);    // elements
    const unsigned short* ApS = A + (size_t)(tm * BM + srow) * GK + scol;
    const unsigned short* BpS0 = Bt + (size_t)(tn * BN + srow) * GK + scol;
    const unsigned short* BpS1 = BpS0 + (size_t)128 * GK;
    const int wbase = (w << 10);                                // w*1024 B

#define STAGE(dstbase)                                                         \
    {                                                                          \
        __builtin_amdgcn_global_load_lds(                                      \
            (const __attribute__((address_space(1))) void*)ApS,                \
            (__attribute__((address_space(3))) void*)(smem + (dstbase) + wbase), 16, 0, 0); \
        __builtin_amdgcn_global_load_lds(                                      \
            (const __attribute__((address_space(1))) void*)BpS0,               \
            (__attribute__((address_space(3))) void*)(smem + (dstbase) + A_LDS + wbase), 16, 0, 0); \
        __builtin_amdgcn_global_load_lds(                                      \
            (const __attribute__((address_space(1))) void*)BpS1,               \
            (__attribute__((address_space(3))) void*)(smem + (dstbase) + A_LDS + 8192 + wbase), 16, 0, 0); \
        ApS += BK; BpS0 += BK; BpS1 += BK;                                     \
    }

    // ---- fragment read addressing (swizzled): byte = row*64 + swslot*16 ----
    const int sw = (((lane >> 4) ^ (((lane & 15) >> 1) & 3)) << 4);
    const int arow = (wm * 64 + (lane & 15)) * 64;              // A row byte
    const int brow = A_LDS + (wn * 64 + (lane & 15)) * 64;      // B row byte

#define LDA(m) (*reinterpret_cast<const f16x8*>(smem + lb + arow + (m) * 1024 + sw))
#define LDB(n) (*reinterpret_cast<const f16x8*>(smem + lb + brow + (n) * 1024 + sw))
#define MFMA_ROW(aR, r)                                                          \
    acc[r][0] = __builtin_amdgcn_mfma_f32_16x16x32_f16(aR, b0, acc[r][0], 0, 0, 0); \
    acc[r][1] = __builtin_amdgcn_mfma_f32_16x16x32_f16(aR, b1, acc[r][1], 0, 0, 0); \
    acc[r][2] = __builtin_amdgcn_mfma_f32_16x16x32_f16(aR, b2, acc[r][2], 0, 0, 0); \
    acc[r][3] = __builtin_amdgcn_mfma_f32_16x16x32_f16(aR, b3, acc[r][3], 0, 0, 0);

    // ---- prologue: stage tile0 -> buf0, tile1 -> buf1; wait own tile0 ----
    STAGE(0)
    STAGE(BUF)
    asm volatile("s_waitcnt vmcnt(3)" ::: "memory");
    __builtin_amdgcn_s_barrier();
    __builtin_amdgcn_sched_barrier(0);

    int lb = 0;            // buffer holding tile t
    int wb = 2 * BUF;      // buffer receiving tile t+2
    for (int t = 0; t < NT; ++t) {
        f16x8 a0, a1, a2, a3, b0, b1, b2, b3;
        a0 = LDA(0); a1 = LDA(1); a2 = LDA(2); a3 = LDA(3);
        b0 = LDB(0); b1 = LDB(1); b2 = LDB(2); b3 = LDB(3);
        if (t + 2 < NT) STAGE(wb)
        asm volatile("s_waitcnt lgkmcnt(0)" ::: "memory");
        __builtin_amdgcn_sched_barrier(0);
        __builtin_amdgcn_s_setprio(1);
        MFMA_ROW(a0, 0) MFMA_ROW(a1, 1) MFMA_ROW(a2, 2) MFMA_ROW(a3, 3)
        __builtin_amdgcn_s_setprio(0);
        // boundary: ensure tile t+1's chunks (all waves) landed
        if (t + 1 < NT) {
            if (t + 2 < NT) {
                asm volatile("s_waitcnt vmcnt(3)" ::: "memory");
            } else {
                asm volatile("s_waitcnt vmcnt(0)" ::: "memory");
            }
            __builtin_amdgcn_s_barrier();
            __builtin_amdgcn_sched_barrier(0);
            lb = (lb == 2 * BUF) ? 0 : lb + BUF;
            wb = (wb == 2 * BUF) ? 0 : wb + BUF;
        }
    }
#undef LDA
#undef LDB
#undef MFMA_ROW
#undef STAGE

    // ---- epilogue: C/D layout col=lane&15, row=(lane>>4)*4+j ----
    const int crow0 = tm * BM + wm * 64 + ((lane >> 4) << 2);
    const int ccol0 = tn * BN + wn * 64 + (lane & 15);
    if constexpr (QUANT) {
        float c[16];
#pragma unroll
        for (int i = 0; i < 16; i++) c[i] = cb16[i];
        unsigned short* O = (unsigned short*)Cout;
#pragma unroll
        for (int m = 0; m < 4; m++)
#pragma unroll
            for (int n = 0; n < 4; n++)
#pragma unroll
                for (int j = 0; j < 4; j++) {
                    const float yn = acc[m][n][j] * 64.0f;
                    float v = c[0];
#pragma unroll
                    for (int i = 0; i < 15; i++) {
                        const float bnd = 0.5f * (c[i] + c[i + 1]);
                        v = (yn > bnd) ? c[i + 1] : v;
                    }
                    O[(size_t)(crow0 + m * 16 + j) * 4096 + ccol0 + n * 16] =
                        f2h(v * 0.015625f);
                }
    } else {
        float* O = (float*)Cout;
#pragma unroll
        for (int m = 0; m < 4; m++)
#pragma unroll
            for (int n = 0; n < 4; n++)
#pragma unroll
                for (int j = 0; j < 4; j++)
                    O[(size_t)(crow0 + m * 16 + j) * 4096 + ccol0 + n * 16] =
                        acc[m][n][j];
    }
}

extern "C" void kernel_launch(void* const* d_in, const int* in_sizes, int n_in,
                              void* d_out, int out_size, void* d_ws,
                              size_t ws_size, hipStream_t stream) {
    const float* x = (const float*)d_in[0];
    const float* rot = (const float*)d_in[1];
    const float* cb = (const float*)d_in[2];
    float* out = (float*)d_out;

    unsigned short* Xh = (unsigned short*)d_ws;
    unsigned short* Rh = Xh + (size_t)2048 * 4096;
    unsigned short* Rt = Rh + (size_t)4096 * 4096;
    unsigned short* Yh = Rt + (size_t)4096 * 4096;

    (void)hipFuncSetAttribute(
        reinterpret_cast<const void*>(&gemm_nt_kernel<true>),
        hipFuncAttributeMaxDynamicSharedMemorySize, LDS_DYN);
    (void)hipFuncSetAttribute(
        reinterpret_cast<const void*>(&gemm_nt_kernel<false>),
        hipFuncAttributeMaxDynamicSharedMemorySize, LDS_DYN);

    convert_x_kernel<<<8192, 256, 0, stream>>>(x, Xh);
    conv_rot_kernel<<<dim3(64, 64), 256, 0, stream>>>(rot, Rh, Rt);
    // y = x @ R^T : NT GEMM, Bt = Rh
    gemm_nt_kernel<true><<<256, 512, LDS_DYN, stream>>>(Xh, Rh, (void*)Yh, cb);
    // x_hat = y_hat @ R = y_hat @ (R^T)^T : NT GEMM, Bt = Rt
    gemm_nt_kernel<false><<<256, 512, LDS_DYN, stream>>>(Yh, Rt, (void*)out, nullptr);
}